// Round 3
// baseline (517.299 us; speedup 1.0000x reference)
//
#include <hip/hip_runtime.h>

typedef __bf16 bf16;
typedef __bf16 bf16x8 __attribute__((ext_vector_type(8)));
typedef __bf16 bf16x4 __attribute__((ext_vector_type(4)));
typedef float f32x4 __attribute__((ext_vector_type(4)));

#define N_DIM 196
#define C_DIM 768
#define B_DIM 256
#define KSTEPS 7           // 7*32 = 224 padded contraction length
#define MT1 14             // GEMM1 M-tiles (freq k padded to 224)
#define MT2 13             // GEMM2 M-tiles (n padded to 208)
#define CT 64              // channels per block
#define NTILES 12          // C_DIM / CT
#define NB 4               // batches per block (pipelined)

#define D2F_ELEMS (MT1 * KSTEPS * 512)          // 50176 bf16
#define EF_ELEMS  (MT2 * KSTEPS * 512)          // 46592 bf16
#define WF_ELEMS  (NTILES * MT1 * 4 * 64 * 4)   // 172032 fp32

// LDS: 64 rows (channels) x 256 elems, bf16, XOR-swizzled on 16B granules.
__device__ __forceinline__ int swz(int row, int off) {
    return row * 256 + ((((off >> 3) ^ ((row >> 2) & 7) ^ ((row & 1) << 2)) << 3) | (off & 7));
}

__global__ void init_mats(const float* __restrict__ wgt,
                          bf16* __restrict__ d2f, bf16* __restrict__ ef,
                          float* __restrict__ wf) {
    int idx = blockIdx.x * 256 + threadIdx.x;
    const float PI = 3.14159265358979323846f;
    if (idx < D2F_ELEMS) {
        int j    = idx & 7;
        int lane = (idx >> 3) & 63;
        int rest = idx >> 9;
        int ks = rest % KSTEPS;
        int mt = rest / KSTEPS;
        int row = mt * 16 + (lane & 15);
        int col = ks * 32 + (lane >> 4) * 8 + j;
        float v = 0.0f;
        if (row < N_DIM && col < N_DIM) {
            int t = ((2 * col + 1) * row) % (4 * N_DIM);
            v = 2.0f * cosf(PI * (float)t / (float)(2 * N_DIM));
        }
        d2f[idx] = (bf16)v;
        return;
    }
    idx -= D2F_ELEMS;
    if (idx < EF_ELEMS) {
        int j    = idx & 7;
        int lane = (idx >> 3) & 63;
        int rest = idx >> 9;
        int ks = rest % KSTEPS;
        int mt = rest / KSTEPS;
        int row = mt * 16 + (lane & 15);
        int col = ks * 32 + (lane >> 4) * 8 + j;
        float v = 0.0f;
        if (row < N_DIM && col < N_DIM) {
            if (col == 0) v = 1.0f / (float)(2 * N_DIM);
            else {
                int t = ((2 * row + 1) * col) % (4 * N_DIM);
                v = cosf(PI * (float)t / (float)(2 * N_DIM)) / (float)N_DIM;
            }
        }
        ef[idx] = (bf16)v;
        return;
    }
    idx -= EF_ELEMS;
    if (idx < WF_ELEMS) {
        int r    = idx & 3;
        int lane = (idx >> 2) & 63;
        int rest = idx >> 8;
        int ct    = rest & 3;
        int rest2 = rest >> 2;
        int mt    = rest2 % MT1;
        int ctile = rest2 / MT1;
        int c = ctile * CT + ct * 16 + (lane & 15);
        int k = mt * 16 + ((lane >> 4) & 3) * 4 + r;
        wf[idx] = (k < N_DIM) ? wgt[(size_t)c * N_DIM + k] : 0.0f;
    }
}

// ---- staging macros (pure vector types, NO address-taking -> no scratch) ----
// half h covers i in {2h, 2h+1}; quad = i*16 + mslot; data quads <= 48.
#define ISSUE_HALF(pf, h, bb)                                                   \
    _Pragma("unroll")                                                           \
    for (int i = 0; i < 2; ++i) {                                               \
        int quad = ((h) * 2 + i) * 16 + mslot;                                  \
        if (quad <= 48) {                                                       \
            const float* p = x + ((size_t)(bb) * N_DIM + quad * 4) * C_DIM + c0 + c4; \
            _Pragma("unroll")                                                   \
            for (int r = 0; r < 4; ++r)                                         \
                pf[i][r] = *(const f32x4*)(p + r * C_DIM);                      \
        }                                                                       \
    }

#define PACK_HALF(pk, pf, h)                                                    \
    _Pragma("unroll")                                                           \
    for (int i = 0; i < 2; ++i) {                                               \
        int quad = ((h) * 2 + i) * 16 + mslot;                                  \
        bool valid = (quad <= 48);                                              \
        _Pragma("unroll")                                                       \
        for (int j = 0; j < 4; ++j) {                                           \
            bf16x4 v;                                                           \
            v[0] = valid ? (bf16)pf[i][0][j] : (bf16)0.0f;                      \
            v[1] = valid ? (bf16)pf[i][1][j] : (bf16)0.0f;                      \
            v[2] = valid ? (bf16)pf[i][2][j] : (bf16)0.0f;                      \
            v[3] = valid ? (bf16)pf[i][3][j] : (bf16)0.0f;                      \
            pk[i][j] = v;                                                       \
        }                                                                       \
    }

#define WRITE_HALF(pk, h)                                                       \
    _Pragma("unroll")                                                           \
    for (int i = 0; i < 2; ++i) {                                               \
        int quad = ((h) * 2 + i) * 16 + mslot;                                  \
        if (quad <= 55) {                                                       \
            _Pragma("unroll")                                                   \
            for (int j = 0; j < 4; ++j)                                         \
                *(bf16x4*)(lds + swz(c4 + j, quad * 4)) = pk[i][j];             \
        }                                                                       \
    }

__global__ __launch_bounds__(256, 3) void dct_fused(
        const float* __restrict__ x, const float* __restrict__ wf,
        const bf16* __restrict__ d2f, const bf16* __restrict__ ef,
        float* __restrict__ out) {
    __shared__ bf16 lds[CT * 256];     // 32 KiB

    const int ctile = blockIdx.x;
    const int b0 = blockIdx.y * NB;
    const int c0 = ctile * CT;
    const int t  = threadIdx.x;
    const int wave = t >> 6;
    const int lane = t & 63;
    const int ln15 = lane & 15;
    const int q    = lane >> 4;
    const int mslot = t >> 4;          // 0..15
    const int c4    = (t & 15) * 4;    // 4 channels per thread

    f32x4 pfa[2][4], pfb[2][4];
    bf16x4 pka[2][4], pkb[2][4];

    // prologue: load + pack batch b0 (one exposed HBM latency per block)
    ISSUE_HALF(pfa, 0, b0)
    ISSUE_HALF(pfb, 1, b0)
    PACK_HALF(pka, pfa, 0)
    PACK_HALF(pkb, pfb, 1)

    for (int it = 0; it < NB; ++it) {
        const int b = b0 + it;
        const bool more = (it + 1 < NB);

        // 1. stage current batch from packed regs
        WRITE_HALF(pka, 0)
        WRITE_HALF(pkb, 1)
        __syncthreads();

        // 2. prefetch half A of next batch (lands during GEMM1)
        if (more) { ISSUE_HALF(pfa, 0, b + 1) }

        // 3. GEMM1: T1[k,c] = sum_m D2[k,m] * x[m,c]
        f32x4 acc[4][4] = {};
#pragma unroll
        for (int ks = 0; ks < KSTEPS; ++ks) {
            bf16x8 bfr0 = *(const bf16x8*)(lds + swz(0 * 16 + ln15, ks * 32 + q * 8));
            bf16x8 bfr1 = *(const bf16x8*)(lds + swz(1 * 16 + ln15, ks * 32 + q * 8));
            bf16x8 bfr2 = *(const bf16x8*)(lds + swz(2 * 16 + ln15, ks * 32 + q * 8));
            bf16x8 bfr3 = *(const bf16x8*)(lds + swz(3 * 16 + ln15, ks * 32 + q * 8));
#pragma unroll
            for (int ml = 0; ml < 4; ++ml) {
                int mt = wave + 4 * ml;
                if (mt < MT1) {
                    bf16x8 afr = *(const bf16x8*)(d2f + ((size_t)(mt * KSTEPS + ks) * 64 + lane) * 8);
                    acc[ml][0] = __builtin_amdgcn_mfma_f32_16x16x32_bf16(afr, bfr0, acc[ml][0], 0, 0, 0);
                    acc[ml][1] = __builtin_amdgcn_mfma_f32_16x16x32_bf16(afr, bfr1, acc[ml][1], 0, 0, 0);
                    acc[ml][2] = __builtin_amdgcn_mfma_f32_16x16x32_bf16(afr, bfr2, acc[ml][2], 0, 0, 0);
                    acc[ml][3] = __builtin_amdgcn_mfma_f32_16x16x32_bf16(afr, bfr3, acc[ml][3], 0, 0, 0);
                }
            }
        }

        // 4. pack half A (loads have had all of GEMM1 to land)
        if (more) { PACK_HALF(pka, pfa, 0) }
        __syncthreads();

        // 5. epilogue: T1w[k,c] = T1[k,c]*w[c,k] -> bf16 back into LDS
#pragma unroll
        for (int ml = 0; ml < 4; ++ml) {
            int mt = wave + 4 * ml;
            if (mt >= MT1) continue;
            int kb = mt * 16 + q * 4;
#pragma unroll
            for (int ct = 0; ct < 4; ++ct) {
                int cc = ct * 16 + ln15;
                f32x4 wv = *(const f32x4*)(wf + ((size_t)((ctile * MT1 + mt) * 4 + ct) * 64 + lane) * 4);
                bf16x4 pv;
                pv[0] = (bf16)(acc[ml][ct][0] * wv[0]);
                pv[1] = (bf16)(acc[ml][ct][1] * wv[1]);
                pv[2] = (bf16)(acc[ml][ct][2] * wv[2]);
                pv[3] = (bf16)(acc[ml][ct][3] * wv[3]);
                *(bf16x4*)(lds + swz(cc, kb)) = pv;
            }
        }
        __syncthreads();

        // 6. prefetch half B of next batch (lands during GEMM2)
        if (more) { ISSUE_HALF(pfb, 1, b + 1) }

        // 7. GEMM2: y[n,c] = sum_k E[n,k] * T1w[k,c]
        f32x4 acc2[4][4] = {};
#pragma unroll
        for (int ks = 0; ks < KSTEPS; ++ks) {
            bf16x8 bfr0 = *(const bf16x8*)(lds + swz(0 * 16 + ln15, ks * 32 + q * 8));
            bf16x8 bfr1 = *(const bf16x8*)(lds + swz(1 * 16 + ln15, ks * 32 + q * 8));
            bf16x8 bfr2 = *(const bf16x8*)(lds + swz(2 * 16 + ln15, ks * 32 + q * 8));
            bf16x8 bfr3 = *(const bf16x8*)(lds + swz(3 * 16 + ln15, ks * 32 + q * 8));
#pragma unroll
            for (int ml = 0; ml < 4; ++ml) {
                int mt = wave + 4 * ml;
                if (mt < MT2) {
                    bf16x8 afr = *(const bf16x8*)(ef + ((size_t)(mt * KSTEPS + ks) * 64 + lane) * 8);
                    acc2[ml][0] = __builtin_amdgcn_mfma_f32_16x16x32_bf16(afr, bfr0, acc2[ml][0], 0, 0, 0);
                    acc2[ml][1] = __builtin_amdgcn_mfma_f32_16x16x32_bf16(afr, bfr1, acc2[ml][1], 0, 0, 0);
                    acc2[ml][2] = __builtin_amdgcn_mfma_f32_16x16x32_bf16(afr, bfr2, acc2[ml][2], 0, 0, 0);
                    acc2[ml][3] = __builtin_amdgcn_mfma_f32_16x16x32_bf16(afr, bfr3, acc2[ml][3], 0, 0, 0);
                }
            }
        }

        // 8. pack half B; store y
        if (more) { PACK_HALF(pkb, pfb, 1) }
#pragma unroll
        for (int ml = 0; ml < 4; ++ml) {
            int mt = wave + 4 * ml;
            if (mt >= MT2) continue;
#pragma unroll
            for (int ct = 0; ct < 4; ++ct) {
                int cc = ct * 16 + ln15;
#pragma unroll
                for (int r = 0; r < 4; ++r) {
                    int n = mt * 16 + q * 4 + r;
                    if (n < N_DIM)
                        out[((size_t)b * N_DIM + n) * C_DIM + c0 + cc] = acc2[ml][ct][r];
                }
            }
        }
        __syncthreads();   // T1w reads done before next staging overwrites
    }
}

extern "C" void kernel_launch(void* const* d_in, const int* in_sizes, int n_in,
                              void* d_out, int out_size, void* d_ws, size_t ws_size,
                              hipStream_t stream) {
    const float* x   = (const float*)d_in[0];   // [256,196,768] fp32
    const float* wgt = (const float*)d_in[1];   // [768,196] fp32
    float* out = (float*)d_out;                 // [256,196,768] fp32

    bf16* d2f  = (bf16*)d_ws;
    bf16* ef   = d2f + D2F_ELEMS;
    float* wfp = (float*)(ef + EF_ELEMS);

    int tot = D2F_ELEMS + EF_ELEMS + WF_ELEMS;
    init_mats<<<(tot + 255) / 256, 256, 0, stream>>>(wgt, d2f, ef, wfp);

    dim3 grid(NTILES, B_DIM / NB);              // 12 x 64 = 768 blocks, 3/CU
    dct_fused<<<grid, 256, 0, stream>>>(x, wfp, d2f, ef, out);
}